// Round 1
// baseline (1447.832 us; speedup 1.0000x reference)
//
#include <hip/hip_runtime.h>
#include <math.h>

typedef unsigned int u32;
typedef unsigned short u16;
typedef unsigned char u8;
typedef __attribute__((ext_vector_type(4))) float f32x4;
typedef __attribute__((ext_vector_type(8))) short bf16x8;

__device__ __forceinline__ u16 f2b(float f){ u32 u=__float_as_uint(f); u=(u+0x7fffu+((u>>16)&1u))>>16; return (u16)u; }
__device__ __forceinline__ float b2f(u16 h){ return __uint_as_float(((u32)h)<<16); }

struct P {
  const float* in[43];
  float* out;
  float* q;          // ws [2048][128] f32
};

//================ StateNet: q0[b][128] ================
__global__ __launch_bounds__(512) void k_state(P p){
  __shared__ float sx1[112];
  __shared__ float sx2[32];
  __shared__ float sa[296];
  __shared__ float sb[296];
  __shared__ float sc2[32];
  __shared__ float sh1[64];
  __shared__ float sh2[16];
  __shared__ float red[512];
  int tid=threadIdx.x; int b=blockIdx.x;
  const float rs_bn = rsqrtf(1.0f+1e-5f);
  const float* x1 = p.in[1] + (size_t)b*111;
  const float* x2 = p.in[2] + (size_t)b*28;
  if (tid<111) sx1[tid]=x1[tid];
  if (tid>=128 && tid<156) sx2[tid-128]=x2[tid-128];
  __syncthreads();
  if (tid<296){
    int cc=tid/37, i=tid-cc*37;
    const float* wgt=p.in[4];
    float acc=p.in[5][cc];
    #pragma unroll
    for(int ic=0;ic<3;++ic)
      #pragma unroll
      for(int kh=0;kh<3;++kh){
        int ii=i+kh-1;
        if((unsigned)ii<37u) acc+=wgt[((cc*3+ic)*3+kh)*3+1]*sx1[ic*37+ii];
      }
    acc=acc*(p.in[6][cc]*rs_bn)+p.in[7][cc];
    sa[tid]=fmaxf(acc,0.f);
  }
  if (tid>=296 && tid<328){
    int o=tid-296, cc=o>>2, i=o&3;
    const float* wgt=p.in[14];
    float acc=p.in[15][cc];
    for(int ic=0;ic<7;++ic)
      for(int kh=0;kh<3;++kh){
        int ii=i+kh-1;
        if((unsigned)ii<4u) acc+=wgt[((cc*7+ic)*3+kh)*3+1]*sx2[ic*4+ii];
      }
    acc=acc*(p.in[16][cc]*rs_bn)+p.in[17][cc];
    sc2[o]=fmaxf(acc,0.f);
  }
  __syncthreads();
  if (tid<296){
    int cc=tid/37, i=tid-cc*37;
    const float* wgt=p.in[8];
    float acc=p.in[9][cc];
    #pragma unroll
    for(int ic=0;ic<8;++ic)
      #pragma unroll
      for(int kh=0;kh<3;++kh){
        int ii=i+kh-1;
        if((unsigned)ii<37u) acc+=wgt[((cc*8+ic)*3+kh)*3+1]*sa[ic*37+ii];
      }
    acc=acc*(p.in[10][cc]*rs_bn)+p.in[11][cc];
    sb[tid]=fmaxf(acc,0.f);
  }
  if (tid>=480 && tid<496){
    int o=tid-480;
    const float* wgt=p.in[18];
    float acc=p.in[19][o];
    for(int k=0;k<32;++k) acc+=sc2[k]*wgt[k*16+o];
    sh2[o]=fmaxf(acc,0.f);
  }
  __syncthreads();
  {
    int o=tid>>3, j=tid&7;
    const float* wgt=p.in[12];
    float part=0.f;
    for(int m=0;m<37;++m){ int k=j*37+m; part+=sb[k]*wgt[k*64+o]; }
    red[o*8+j]=part;
  }
  __syncthreads();
  if (tid<64){
    float acc=p.in[13][tid];
    #pragma unroll
    for(int j=0;j<8;++j) acc+=red[tid*8+j];
    sh1[tid]=fmaxf(acc,0.f);
  }
  __syncthreads();
  if (tid<128){
    const float* wgt=p.in[20];
    const float* x3=p.in[3]+(size_t)b*4;
    float acc=p.in[21][tid];
    for(int k=0;k<64;++k) acc+=sh1[k]*wgt[k*128+tid];
    for(int k=0;k<16;++k) acc+=sh2[k]*wgt[(64+k)*128+tid];
    #pragma unroll
    for(int k=0;k<4;++k) acc+=x3[k]*wgt[(80+k)*128+tid];
    p.q[(size_t)b*128+tid]=fmaxf(acc,0.f);
  }
}

//================ Fused decoder: LN(enc)->LDS, 3x(attn+post), head — one block per b ================
// LDS map (bytes):
//   XH   [512][136] u16   @ 0        (139264)  xhat bf16, persistent
//   WTU  union            @ 139264   (16640)
//     phase Q/Qk : red f32[512]@+0, qxs f32[128]@+2048, Qs f32[128]@+2560, QKb u16[16][136]@+3072
//     softmax/PV : WT u16[16][520]@+0 (full)
//     post       : SS f32[8][132]@+0, red2 f32[512]@+4224, atts[128]@+6272, qps[128]@+6784,
//                  qx4[128]@+7296, us f32[512]@+7808
//   qv   f32[128]         @ 155904
//   wred f32[128]         @ 156416
//   mrow f32[16]          @ 156928
//   invL f32[16]          @ 156992
//   st   f32[2]           @ 157056
#define FUSED_LDS 157184

__global__ __launch_bounds__(512,1) void k_fused(P p){
  extern __shared__ u8 sm[];
  u16*  XH   = (u16*)sm;
  u8*   WTU  = sm + 139264;
  float* qv   = (float*)(sm + 155904);
  float* wred = (float*)(sm + 156416);
  float* mrow = (float*)(sm + 156928);
  float* invL = (float*)(sm + 156992);
  float* st   = (float*)(sm + 157056);

  float* red  = (float*)(WTU);
  float* qxs  = (float*)(WTU + 2048);
  float* Qs   = (float*)(WTU + 2560);
  u16*  QKb   = (u16*)(WTU + 3072);
  u16*  WT    = (u16*)(WTU);
  float* SS   = (float*)(WTU);
  float* red2 = (float*)(WTU + 4224);
  float* atts = (float*)(WTU + 6272);
  float* qps  = (float*)(WTU + 6784);
  float* qx4  = (float*)(WTU + 7296);
  float* us   = (float*)(WTU + 7808);

  int tid=threadIdx.x;
  int w = tid>>6, lane = tid&63, l15 = lane&15, q4 = lane>>4;
  int b = blockIdx.x;

  // ---- stage: LN(enc[b]) -> XH bf16 (read enc once, keep resident for all 3 layers) ----
  {
    const float* enc = p.in[0] + (size_t)b*512*128;
    int g = tid>>5, c = tid&31;
    #pragma unroll 4
    for (int it=0; it<32; ++it){
      int row = it*16 + g;
      float4 v = *(const float4*)(enc + (size_t)row*128 + c*4);
      float s = v.x+v.y+v.z+v.w;
      float s2 = v.x*v.x+v.y*v.y+v.z*v.z+v.w*v.w;
      #pragma unroll
      for (int m=1; m<=16; m<<=1){ s+=__shfl_xor(s,m); s2+=__shfl_xor(s2,m); }
      float mean = s*(1.f/128.f);
      float rstd = rsqrtf(s2*(1.f/128.f)-mean*mean+1e-5f);
      u32 a = (u32)f2b((v.x-mean)*rstd) | ((u32)f2b((v.y-mean)*rstd)<<16);
      u32 bq= (u32)f2b((v.z-mean)*rstd) | ((u32)f2b((v.w-mean)*rstd)<<16);
      *(uint2*)(XH + row*136 + c*4) = make_uint2(a,bq);
    }
    if (tid<128) qv[tid] = p.q[(size_t)b*128 + tid];
  }
  __syncthreads();

  for (int l=0; l<3; ++l){
    const float* wk = p.in[22] + l*16384;
    const float* wq = p.in[23] + l*16384;
    const float* wv = p.in[24] + l*16384;
    const float* pw = p.in[25] + l*16384;
    const float* pb = p.in[26] + l*128;
    const float* g1 = p.in[27] + l*128;
    const float* g2 = p.in[29] + l*128;
    const float* b2v= p.in[30] + l*128;
    const float* g3 = p.in[31] + l*128;
    const float* b3 = p.in[32] + l*128;
    const float* g4 = p.in[33] + l*128;
    const float* b4 = p.in[34] + l*128;
    const float* f1 = p.in[35] + l*65536;
    const float* fb1= p.in[36] + l*512;
    const float* f2 = p.in[37] + l*65536;
    const float* fb2= p.in[38] + l*128;

    // ---- LN3(q) ----
    if (w==0){
      float x0=qv[lane], x1=qv[lane+64];
      float s=x0+x1, s2=x0*x0+x1*x1;
      #pragma unroll
      for(int m=1;m<=32;m<<=1){ s+=__shfl_xor(s,m); s2+=__shfl_xor(s2,m); }
      if(lane==0){ float mean=s*(1.f/128.f); st[0]=mean; st[1]=rsqrtf(s2*(1.f/128.f)-mean*mean+1e-5f); }
    }
    __syncthreads();
    if (tid<128) qxs[tid]=(qv[tid]-st[0])*st[1]*g3[tid]+b3[tid];
    __syncthreads();

    // ---- Q = qx @ wq (k-split 4) ----
    {
      int o = tid&127, kk = tid>>7;
      float acc=0.f;
      const float* wp = wq + kk*32*128 + o;
      #pragma unroll 8
      for (int e=0;e<32;++e) acc += qxs[kk*32+e]*wp[e*128];
      red[tid]=acc;
    }
    __syncthreads();
    if (tid<128) Qs[tid]=red[tid]+red[tid+128]+red[tid+256]+red[tid+384];
    __syncthreads();

    // ---- Qk[h][e] = 4*g1[e]*sum_d Q[h,d]*wk[e, h*16+d]  (rows 8..15 zero-padded) ----
    {
      int h = tid>>5, e0=(tid&31)*4;
      if (h<8){
        float Qh[16];
        #pragma unroll
        for(int d=0;d<16;++d) Qh[d]=Qs[h*16+d];
        #pragma unroll
        for(int j=0;j<4;++j){
          int e=e0+j;
          const float* wr = wk + e*128 + h*16;
          float4 wv0=*(const float4*)(wr), wv1=*(const float4*)(wr+4), wv2=*(const float4*)(wr+8), wv3=*(const float4*)(wr+12);
          float acc = Qh[0]*wv0.x+Qh[1]*wv0.y+Qh[2]*wv0.z+Qh[3]*wv0.w
                    + Qh[4]*wv1.x+Qh[5]*wv1.y+Qh[6]*wv1.z+Qh[7]*wv1.w
                    + Qh[8]*wv2.x+Qh[9]*wv2.y+Qh[10]*wv2.z+Qh[11]*wv2.w
                    + Qh[12]*wv3.x+Qh[13]*wv3.y+Qh[14]*wv3.z+Qh[15]*wv3.w;
          QKb[h*136+e] = f2b(acc*g1[e]*4.f);
        }
      } else {
        #pragma unroll
        for(int j=0;j<4;++j) QKb[h*136+e0+j]=0;
      }
    }
    __syncthreads();

    // B-fragments of Qk held in registers
    bf16x8 qkf[4];
    #pragma unroll
    for(int ks=0;ks<4;++ks) qkf[ks]=*(const bf16x8*)(QKb + l15*136 + ks*32 + q4*8);

    // ---- scores: D[t][h], wave w owns t in [64w,64w+64) as 4 m-blocks ----
    f32x4 sc[4];
    #pragma unroll
    for(int mb=0;mb<4;++mb){
      f32x4 c = {0.f,0.f,0.f,0.f};
      #pragma unroll
      for(int ks=0;ks<4;++ks){
        bf16x8 a = *(const bf16x8*)(XH + (64*w + 16*mb + l15)*136 + ks*32 + q4*8);
        c = __builtin_amdgcn_mfma_f32_16x16x32_bf16(a, qkf[ks], c, 0,0,0);
      }
      sc[mb]=c;
    }
    // per-h max over all 512 t
    {
      float mx = -INFINITY;
      #pragma unroll
      for(int mb=0;mb<4;++mb)
        #pragma unroll
        for(int r=0;r<4;++r) mx = fmaxf(mx, sc[mb][r]);
      mx = fmaxf(mx, __shfl_xor(mx,16)); mx = fmaxf(mx, __shfl_xor(mx,32));
      if (lane<16) wred[w*16+lane]=mx;
    }
    __syncthreads();
    if (tid<16){
      float m0=wred[tid];
      #pragma unroll
      for(int ww=1;ww<8;++ww) m0=fmaxf(m0, wred[ww*16+tid]);
      mrow[tid]=m0;
    }
    __syncthreads();
    // exp -> WT[h][t] bf16, per-h sums
    {
      float mh = mrow[l15];
      float ssum=0.f;
      #pragma unroll
      for(int mb=0;mb<4;++mb)
        #pragma unroll
        for(int r=0;r<4;++r){
          int t = 64*w + 16*mb + q4*4 + r;
          float pv = __expf(sc[mb][r]-mh);
          ssum += pv;
          WT[l15*520 + t] = f2b(pv);
        }
      ssum += __shfl_xor(ssum,16); ssum += __shfl_xor(ssum,32);
      if (lane<16) wred[w*16+lane]=ssum;
    }
    __syncthreads();
    if (tid<16) invL[tid] = 1.f/(wred[tid]+wred[16+tid]+wred[32+tid]+wred[48+tid]
                                +wred[64+tid]+wred[80+tid]+wred[96+tid]+wred[112+tid]);
    __syncthreads();

    // ---- PV: att[h][e], wave w owns e-strip [16w,16w+16) ----
    f32x4 wa = {0.f,0.f,0.f,0.f};
    int eb = w*16 + l15;
    #pragma unroll 4
    for(int ks=0;ks<16;++ks){
      bf16x8 aw = *(const bf16x8*)(WT + l15*520 + ks*32 + q4*8);
      bf16x8 bb;
      #pragma unroll
      for(int j=0;j<8;++j){
        int t = ks*32 + q4*8 + j;
        bb[j] = (short)XH[t*136 + eb];
      }
      wa = __builtin_amdgcn_mfma_f32_16x16x32_bf16(aw, bb, wa, 0,0,0);
    }
    __syncthreads();   // WT dead; WTU becomes post-phase union
    // SS[h][e] = att*invL*g2 + b2  (b2 folds in since sum_t wei = 1)
    if (q4 < 2){
      float g2e = g2[eb], b2e = b2v[eb];
      #pragma unroll
      for(int r=0;r<4;++r){
        int h = q4*4+r;
        SS[h*132+eb] = wa[r]*invL[h]*g2e + b2e;
      }
    }
    __syncthreads();

    // ---- att_o[o] = sum_e SS[o>>4][e]*wv[e][o] ----
    {
      int o = tid&127, kk = tid>>7; int h=o>>4;
      float acc=0.f;
      const float* wp = wv + kk*32*128 + o;
      const float* Sr = SS + h*132 + kk*32;
      #pragma unroll 8
      for(int e=0;e<32;++e) acc += Sr[e]*wp[e*128];
      red2[tid]=acc;
    }
    __syncthreads();
    if (tid<128) atts[tid]=red2[tid]+red2[tid+128]+red2[tid+256]+red2[tid+384];
    __syncthreads();

    // ---- q' = q + att@pw + pb ----
    {
      int o = tid&127, kk = tid>>7;
      float acc=0.f;
      const float* wp = pw + kk*32*128 + o;
      #pragma unroll 8
      for(int e=0;e<32;++e) acc += atts[kk*32+e]*wp[e*128];
      red2[tid]=acc;
    }
    __syncthreads();
    if (tid<128) qps[tid]= qv[tid] + pb[tid] + red2[tid]+red2[tid+128]+red2[tid+256]+red2[tid+384];
    __syncthreads();

    // ---- LN4 ----
    if (w==0){
      float x0=qps[lane], x1=qps[lane+64];
      float s=x0+x1, s2=x0*x0+x1*x1;
      #pragma unroll
      for(int m=1;m<=32;m<<=1){ s+=__shfl_xor(s,m); s2+=__shfl_xor(s2,m); }
      if(lane==0){ float mean=s*(1.f/128.f); st[0]=mean; st[1]=rsqrtf(s2*(1.f/128.f)-mean*mean+1e-5f); }
    }
    __syncthreads();
    if (tid<128) qx4[tid]=(qps[tid]-st[0])*st[1]*g4[tid]+b4[tid];
    __syncthreads();

    // ---- u = gelu(qx4 @ f1 + fb1) ----
    {
      int o = tid;
      float acc=fb1[o];
      const float* wp = f1 + o;
      #pragma unroll 8
      for(int e=0;e<128;++e) acc += qx4[e]*wp[e*512];
      us[o]=0.5f*acc*(1.f+erff(acc*0.70710678118654752f));
    }
    __syncthreads();

    // ---- q'' = q' + u @ f2 + fb2 ----
    {
      int o = tid&127, kk = tid>>7;
      float acc=0.f;
      const float* wp = f2 + kk*128*128 + o;
      #pragma unroll 8
      for(int e=0;e<128;++e) acc += us[kk*128+e]*wp[e*128];
      red2[tid]=acc;
    }
    __syncthreads();
    if (tid<128) qv[tid]= qps[tid] + fb2[tid] + red2[tid]+red2[tid+128]+red2[tid+256]+red2[tid+384];
    __syncthreads();
  }

  // ---- final LN + head ----
  if (w==0){
    float x0=qv[lane], x1=qv[lane+64];
    float s=x0+x1, s2=x0*x0+x1*x1;
    #pragma unroll
    for(int m=1;m<=32;m<<=1){ s+=__shfl_xor(s,m); s2+=__shfl_xor(s2,m); }
    if(lane==0){ float mean=s*(1.f/128.f); st[0]=mean; st[1]=rsqrtf(s2*(1.f/128.f)-mean*mean+1e-5f); }
  }
  __syncthreads();
  if (tid<128) qx4[tid]=(qv[tid]-st[0])*st[1]*p.in[39][tid]+p.in[40][tid];
  __syncthreads();
  if (tid<37){
    const float* hw=p.in[41];
    float acc=p.in[42][tid];
    #pragma unroll 4
    for(int e=0;e<128;++e) acc += qx4[e]*hw[e*37+tid];
    p.out[(size_t)b*37+tid]=acc;
  }
}

extern "C" void kernel_launch(void* const* d_in, const int* in_sizes, int n_in,
                              void* d_out, int out_size, void* d_ws, size_t ws_size,
                              hipStream_t stream) {
  (void)in_sizes; (void)n_in; (void)out_size; (void)ws_size;
  P pa;
  for(int i=0;i<43;++i) pa.in[i]=(const float*)d_in[i];
  pa.out=(float*)d_out;
  pa.q=(float*)d_ws;   // 1 MB
  static bool inited=false;
  if (!inited){
    hipFuncSetAttribute(reinterpret_cast<const void*>(k_fused),
                        hipFuncAttributeMaxDynamicSharedMemorySize, FUSED_LDS);
    inited=true;
  }
  k_state<<<2048,512,0,stream>>>(pa);
  k_fused<<<2048,512,FUSED_LDS,stream>>>(pa);
}